// Round 1
// baseline (384.611 us; speedup 1.0000x reference)
//
#include <hip/hip_runtime.h>
#include <hip/hip_bf16.h>
#include <stdint.h>

#define T_TOK 131072
#define DIM   512
#define NBR   8

#define BM    64
#define BK    32
#define NKT   (DIM / BK)   // 16
#define GT    512          // gemm threads (8 waves)

typedef __attribute__((ext_vector_type(8))) __bf16 bf16x8;
typedef __attribute__((ext_vector_type(4))) float  f32x4;

__device__ __forceinline__ unsigned short f2bf(float f) {
  union { float f; unsigned int u; } v; v.f = f;
  unsigned int r = v.u + 0x7fffu + ((v.u >> 16) & 1u);
  return (unsigned short)(r >> 16);
}

// ---------------- prep kernels ----------------

__global__ void k_init(int* counts) {
  if (threadIdx.x < NBR) counts[threadIdx.x] = 0;
}

__global__ void k_hist(const int* __restrict__ bidx, int* __restrict__ counts) {
  __shared__ int h[NBR];
  if (threadIdx.x < NBR) h[threadIdx.x] = 0;
  __syncthreads();
  int t = blockIdx.x * blockDim.x + threadIdx.x;
  int stride = gridDim.x * blockDim.x;
  for (; t < T_TOK; t += stride) atomicAdd(&h[bidx[t]], 1);
  __syncthreads();
  if (threadIdx.x < NBR) atomicAdd(&counts[threadIdx.x], h[threadIdx.x]);
}

__global__ void k_offsets(const int* __restrict__ counts, int* __restrict__ offsets,
                          int* __restrict__ cursors) {
  if (threadIdx.x == 0) {
    int s = 0;
    for (int n = 0; n < NBR; ++n) { offsets[n] = s; cursors[n] = s; s += counts[n]; }
  }
}

__global__ void k_scatter(const int* __restrict__ bidx, int* __restrict__ cursors,
                          int* __restrict__ perm) {
  int t = blockIdx.x * blockDim.x + threadIdx.x;
  int stride = gridDim.x * blockDim.x;
  int lane = threadIdx.x & 63;
  for (; t < T_TOK; t += stride) {
    int b = bidx[t];
    int pos = 0;
    #pragma unroll
    for (int n = 0; n < NBR; ++n) {
      unsigned long long m = __ballot(b == n);
      if (m) {
        int leader = (int)__builtin_ctzll(m);
        int base = 0;
        if (lane == leader) base = atomicAdd(&cursors[n], (int)__popcll(m));
        base = __shfl(base, leader, 64);
        if (b == n) pos = base + (int)__popcll(m & ((1ull << lane) - 1ull));
      }
    }
    perm[pos] = t;
  }
}

// W (N,D,D) fp32 row-major -> Wt bf16 tiled [b][kt][c][kk], kk = k % 32
__global__ __launch_bounds__(256) void k_wtrans(const float* __restrict__ W,
                                                unsigned short* __restrict__ Wt) {
  __shared__ float tile[BK][129];
  int blk = blockIdx.x;          // 8 * 16 * 4 = 512 blocks
  int b  = blk >> 6;
  int kt = (blk >> 2) & 15;
  int cb = blk & 3;
  int t = threadIdx.x;
  #pragma unroll
  for (int i = 0; i < 4; ++i) {
    int idx4 = i * 256 + t;      // 0..1023 float4s
    int kr = idx4 >> 5;          // 0..31
    int c4 = idx4 & 31;          // 0..31
    const float* src = W + (((size_t)b * DIM + (size_t)(kt * BK + kr)) * DIM + cb * 128 + c4 * 4);
    float4 v = *(const float4*)src;
    tile[kr][c4 * 4 + 0] = v.x;
    tile[kr][c4 * 4 + 1] = v.y;
    tile[kr][c4 * 4 + 2] = v.z;
    tile[kr][c4 * 4 + 3] = v.w;
  }
  __syncthreads();
  int c  = t >> 1;               // 0..127 (col within 128-chunk)
  int kh = t & 1;                // half of the 32 kk
  unsigned int p[8];
  #pragma unroll
  for (int i = 0; i < 8; ++i) {
    unsigned short lo = f2bf(tile[kh * 16 + i * 2 + 0][c]);
    unsigned short hi = f2bf(tile[kh * 16 + i * 2 + 1][c]);
    p[i] = (unsigned int)lo | ((unsigned int)hi << 16);
  }
  size_t obase = (((size_t)b * 16 + kt) * DIM + (size_t)(cb * 128 + c)) * BK + kh * 16;
  uint4 q0; q0.x = p[0]; q0.y = p[1]; q0.z = p[2]; q0.w = p[3];
  uint4 q1; q1.x = p[4]; q1.y = p[5]; q1.z = p[6]; q1.w = p[7];
  *(uint4*)&Wt[obase]     = q0;
  *(uint4*)&Wt[obase + 8] = q1;
}

// ---------------- grouped GEMM ----------------
// block: BM=64 rows of one branch x all 512 cols. 8 waves, wave = 64x64.
__global__ __launch_bounds__(GT, 4)
void k_gemm(const float* __restrict__ x, const float* __restrict__ bias,
            const unsigned short* __restrict__ Wt,
            const int* __restrict__ counts, const int* __restrict__ offsets,
            const int* __restrict__ perm, float* __restrict__ out) {
  __shared__ __align__(16) unsigned short As[2][BM * 40];     // padded stride 40
  __shared__ __align__(16) unsigned short Bs[2][BK * DIM];    // swizzled chunks, linear p*8
  __shared__ int rowIdx[BM];

  const int tid = threadIdx.x;
  const int l = tid & 63;
  const int w = tid >> 6;

  // block -> (branch, row tile)
  int tile = blockIdx.x;
  int b = -1, lt = 0, accT = 0;
  #pragma unroll
  for (int n = 0; n < NBR; ++n) {
    int cn = counts[n];
    int nt = (cn + BM - 1) / BM;
    if (b < 0 && tile < accT + nt) { b = n; lt = tile - accT; }
    accT += nt;
  }
  if (b < 0) return;
  const int cnt = counts[b];
  const int gstart = offsets[b];
  const int row0 = lt * BM;
  const int vrows = min(BM, cnt - row0);

  if (tid < BM) {
    int r = row0 + tid; if (r >= cnt) r = cnt - 1;
    rowIdx[tid] = perm[gstart + r];
  }
  __syncthreads();

  // A staging: thread -> (row, float4-within-32k)
  const int arow = tid >> 3;
  const int kq = tid & 7;
  const float* aptr = x + (size_t)rowIdx[arow] * DIM + kq * 4;

  const unsigned short* wtile = Wt + (size_t)b * (NKT * BK * DIM);

  // B staging: physical chunk p = i*512+tid holds global chunk q (XOR swizzle)
  int qoff[4];
  #pragma unroll
  for (int i = 0; i < 4; ++i) {
    int p = i * 512 + tid;
    int q = (p & ~3) | ((p & 3) ^ ((p >> 3) & 3));
    qoff[i] = q * 8;
  }

  // fragment read offsets
  const int a_off = (l & 15) * 40 + (l >> 4) * 8;   // + rf*640
  int b_off[4];
  #pragma unroll
  for (int cf = 0; cf < 4; ++cf) {
    int c = w * 64 + cf * 16 + (l & 15);
    int kgp = (l >> 4) ^ ((c >> 1) & 3);
    b_off[cf] = c * 32 + kgp * 8;
  }

  f32x4 acc[4][4];
  #pragma unroll
  for (int rf = 0; rf < 4; ++rf) {
    #pragma unroll
    for (int cf = 0; cf < 4; ++cf) acc[rf][cf] = (f32x4){0.f, 0.f, 0.f, 0.f};
  }

  // prologue: stage kt=0 into buf 0
  {
    #pragma unroll
    for (int i = 0; i < 4; ++i) {
      uint4 bq = *(const uint4*)(wtile + qoff[i]);
      *(uint4*)&Bs[0][i * 4096 + tid * 8] = bq;
    }
    float4 av = *(const float4*)aptr;
    ushort4 a4;
    a4.x = f2bf(av.x); a4.y = f2bf(av.y); a4.z = f2bf(av.z); a4.w = f2bf(av.w);
    *(ushort4*)&As[0][arow * 40 + kq * 4] = a4;
  }
  __syncthreads();

  int cur = 0;
  for (int kt = 0; kt < NKT; ++kt) {
    uint4 bq[4]; float4 av;
    const bool pre = (kt + 1 < NKT);
    if (pre) {  // issue next-tile global loads before compute (latency overlap)
      const unsigned short* wtk = wtile + (size_t)(kt + 1) * (BK * DIM);
      #pragma unroll
      for (int i = 0; i < 4; ++i) bq[i] = *(const uint4*)(wtk + qoff[i]);
      av = *(const float4*)(aptr + (kt + 1) * BK);
    }
    const unsigned short* asrc = As[cur];
    const unsigned short* bsrc = Bs[cur];
    bf16x8 af[4];
    #pragma unroll
    for (int rf = 0; rf < 4; ++rf) af[rf] = *(const bf16x8*)&asrc[rf * 640 + a_off];
    #pragma unroll
    for (int cf = 0; cf < 4; ++cf) {
      bf16x8 bfv = *(const bf16x8*)&bsrc[b_off[cf]];
      #pragma unroll
      for (int rf = 0; rf < 4; ++rf)
        acc[rf][cf] = __builtin_amdgcn_mfma_f32_16x16x32_bf16(af[rf], bfv, acc[rf][cf], 0, 0, 0);
    }
    if (pre) {  // write staged data into the other buffer
      unsigned short* bd = &Bs[cur ^ 1][tid * 8];
      *(uint4*)(bd)         = bq[0];
      *(uint4*)(bd + 4096)  = bq[1];
      *(uint4*)(bd + 8192)  = bq[2];
      *(uint4*)(bd + 12288) = bq[3];
      ushort4 a4;
      a4.x = f2bf(av.x); a4.y = f2bf(av.y); a4.z = f2bf(av.z); a4.w = f2bf(av.w);
      *(ushort4*)&As[cur ^ 1][arow * 40 + kq * 4] = a4;
    }
    __syncthreads();
    cur ^= 1;
  }

  // epilogue: bias add + scattered row store (cols contiguous per 16-lane group)
  float bv[4];
  #pragma unroll
  for (int cf = 0; cf < 4; ++cf) bv[cf] = bias[b * DIM + w * 64 + cf * 16 + (l & 15)];
  const int rb = (l >> 4) * 4;
  #pragma unroll
  for (int rf = 0; rf < 4; ++rf) {
    #pragma unroll
    for (int j = 0; j < 4; ++j) {
      int r = rf * 16 + rb + j;
      if (r < vrows) {
        float* op = out + (size_t)rowIdx[r] * DIM + w * 64 + (l & 15);
        #pragma unroll
        for (int cf = 0; cf < 4; ++cf) op[cf * 16] = acc[rf][cf][j] + bv[cf];
      }
    }
  }
}

// ---------------- launcher ----------------
// ws layout: [0,32) counts | [64,96) cursors | [128,160) offsets |
//            [256, 256+4T) perm | [1MB, 1MB+4MB) Wt bf16
extern "C" void kernel_launch(void* const* d_in, const int* in_sizes, int n_in,
                              void* d_out, int out_size, void* d_ws, size_t ws_size,
                              hipStream_t stream) {
  const float* x    = (const float*)d_in[0];
  const int*   bidx = (const int*)d_in[1];
  const float* W    = (const float*)d_in[2];
  const float* bias = (const float*)d_in[3];
  float* out = (float*)d_out;

  char* ws = (char*)d_ws;
  int* counts  = (int*)(ws + 0);
  int* cursors = (int*)(ws + 64);
  int* offsets = (int*)(ws + 128);
  int* perm    = (int*)(ws + 256);
  unsigned short* Wt = (unsigned short*)(ws + (1u << 20));

  k_init<<<1, 64, 0, stream>>>(counts);
  k_hist<<<256, 256, 0, stream>>>(bidx, counts);
  k_offsets<<<1, 64, 0, stream>>>(counts, offsets, cursors);
  k_scatter<<<256, 256, 0, stream>>>(bidx, cursors, perm);
  k_wtrans<<<512, 256, 0, stream>>>(W, Wt);
  k_gemm<<<T_TOK / BM + NBR, GT, 0, stream>>>(x, bias, Wt, counts, offsets, perm, out);
}

// Round 2
// 206.101 us; speedup vs baseline: 1.8661x; 1.8661x over previous
//
#include <hip/hip_runtime.h>
#include <hip/hip_bf16.h>
#include <stdint.h>

#define T_TOK 131072
#define DIM   512
#define NBR   8
#define BM    64
#define BK    32
#define NKT   (DIM / BK)   // 16
#define GT    512          // gemm threads (8 waves)
#define MT    288          // max row-tiles per branch (E=256, +19 sigma safety)

typedef __attribute__((ext_vector_type(8))) __bf16 bf16x8;
typedef __attribute__((ext_vector_type(4))) float  f32x4;

__device__ __forceinline__ unsigned short f2bf(float f) {
  union { float f; unsigned int u; } v; v.f = f;
  unsigned int r = v.u + 0x7fffu + ((v.u >> 16) & 1u);
  return (unsigned short)(r >> 16);
}

// ---------------- prep kernels ----------------

__global__ void k_init(int* counts) {
  if (threadIdx.x < NBR) counts[threadIdx.x] = 0;
}

// per-block LDS histogram; one global atomic per (block, branch)
__global__ __launch_bounds__(512) void k_bhist(const int* __restrict__ bidx,
                                               int* __restrict__ counts) {
  __shared__ int h[NBR];
  if (threadIdx.x < NBR) h[threadIdx.x] = 0;
  __syncthreads();
  int t = blockIdx.x * 512 + threadIdx.x;   // 256 blocks x 512 = T_TOK exactly
  atomicAdd(&h[bidx[t]], 1);
  __syncthreads();
  if (threadIdx.x < NBR) atomicAdd(&counts[threadIdx.x], h[threadIdx.x]);
}

__global__ void k_off(const int* __restrict__ counts, int* __restrict__ offsets,
                      int* __restrict__ cursors) {
  if (threadIdx.x == 0) {
    int s = 0;
    for (int n = 0; n < NBR; ++n) { offsets[n] = s; cursors[n] = s; s += counts[n]; }
  }
}

// block claims one chunk per branch via ONE global atomic, ranks tokens via LDS
__global__ __launch_bounds__(512) void k_scatter(const int* __restrict__ bidx,
                                                 int* __restrict__ cursors,
                                                 int* __restrict__ perm) {
  __shared__ int h[NBR], base[NBR];
  if (threadIdx.x < NBR) h[threadIdx.x] = 0;
  __syncthreads();
  int t = blockIdx.x * 512 + threadIdx.x;
  int b = bidx[t];
  int rank = atomicAdd(&h[b], 1);           // local rank within (block, branch)
  __syncthreads();
  if (threadIdx.x < NBR)
    base[threadIdx.x] = atomicAdd(&cursors[threadIdx.x], h[threadIdx.x]);
  __syncthreads();
  perm[base[b] + rank] = t;
}

// W (N,D,D) fp32 row-major -> Wt bf16 tiled [b][kt][c][kk], kk = k % 32
__global__ __launch_bounds__(256) void k_wtrans(const float* __restrict__ W,
                                                unsigned short* __restrict__ Wt) {
  __shared__ float tile[BK][129];
  int blk = blockIdx.x;          // 8 * 16 * 4 = 512 blocks
  int b  = blk >> 6;
  int kt = (blk >> 2) & 15;
  int cb = blk & 3;
  int t = threadIdx.x;
  #pragma unroll
  for (int i = 0; i < 4; ++i) {
    int idx4 = i * 256 + t;      // 0..1023 float4s
    int kr = idx4 >> 5;          // 0..31
    int c4 = idx4 & 31;          // 0..31
    const float* src = W + (((size_t)b * DIM + (size_t)(kt * BK + kr)) * DIM + cb * 128 + c4 * 4);
    float4 v = *(const float4*)src;
    tile[kr][c4 * 4 + 0] = v.x;
    tile[kr][c4 * 4 + 1] = v.y;
    tile[kr][c4 * 4 + 2] = v.z;
    tile[kr][c4 * 4 + 3] = v.w;
  }
  __syncthreads();
  int c  = t >> 1;               // 0..127 (col within 128-chunk)
  int kh = t & 1;                // half of the 32 kk
  unsigned int p[8];
  #pragma unroll
  for (int i = 0; i < 8; ++i) {
    unsigned short lo = f2bf(tile[kh * 16 + i * 2 + 0][c]);
    unsigned short hi = f2bf(tile[kh * 16 + i * 2 + 1][c]);
    p[i] = (unsigned int)lo | ((unsigned int)hi << 16);
  }
  size_t obase = (((size_t)b * 16 + kt) * DIM + (size_t)(cb * 128 + c)) * BK + kh * 16;
  uint4 q0; q0.x = p[0]; q0.y = p[1]; q0.z = p[2]; q0.w = p[3];
  uint4 q1; q1.x = p[4]; q1.y = p[5]; q1.z = p[6]; q1.w = p[7];
  *(uint4*)&Wt[obase]     = q0;
  *(uint4*)&Wt[obase + 8] = q1;
}

// ---------------- grouped GEMM ----------------
// block: 64 rows of one branch x all 512 cols. 8 waves, wave = 64x64.
// A (x rows, fp32->bf16) staged in LDS double-buffer, depth-2 reg prefetch.
// B (Wt, L2-resident) loaded straight into VGPR fragments, depth-1 prefetch.
__global__ __launch_bounds__(GT, 4)
void k_gemm(const float* __restrict__ x, const float* __restrict__ bias,
            const unsigned short* __restrict__ Wt,
            const int* __restrict__ counts, const int* __restrict__ offsets,
            const int* __restrict__ perm, float* __restrict__ out) {
  __shared__ __align__(16) unsigned short As[2][BM * 40];   // padded stride 40
  __shared__ int rowIdx[BM];

  const int tid = threadIdx.x;
  const int l = tid & 63;
  const int w = tid >> 6;

  const int b  = blockIdx.x / MT;     // branch-major: dispatch window spans <=2 branches
  const int lt = blockIdx.x % MT;
  const int cnt = counts[b];
  const int row0 = lt * BM;
  if (row0 >= cnt) return;
  const int gstart = offsets[b];
  const int vrows = min(BM, cnt - row0);

  if (tid < BM) {
    int r = row0 + tid; if (r >= cnt) r = cnt - 1;
    rowIdx[tid] = perm[gstart + r];
  }
  __syncthreads();

  // A staging map: thread -> (row, float4-within-32k)
  const int arow = tid >> 3;
  const int kq = tid & 7;
  const float* aptr = x + (size_t)rowIdx[arow] * DIM + kq * 4;

  // B fragment per-lane base within a kt tile: col*32 + kgroup*8 (fully coalesced)
  const unsigned short* wtile = Wt + (size_t)b * (NKT * BK * DIM);
  int bBase[4];
  #pragma unroll
  for (int cf = 0; cf < 4; ++cf)
    bBase[cf] = (w * 64 + cf * 16 + (l & 15)) * BK + (l >> 4) * 8;

  const int a_off = (l & 15) * 40 + (l >> 4) * 8;   // + rf*640

  f32x4 acc[4][4];
  #pragma unroll
  for (int rf = 0; rf < 4; ++rf)
    #pragma unroll
    for (int cf = 0; cf < 4; ++cf) acc[rf][cf] = (f32x4){0.f, 0.f, 0.f, 0.f};

  // prologue: stage kt=0 into As[0]; hold kt=1 x-data in regs; B frags for kt=0
  {
    float4 av0 = *(const float4*)aptr;
    ushort4 a4;
    a4.x = f2bf(av0.x); a4.y = f2bf(av0.y); a4.z = f2bf(av0.z); a4.w = f2bf(av0.w);
    *(ushort4*)&As[0][arow * 40 + kq * 4] = a4;
  }
  float4 av1 = *(const float4*)(aptr + BK);
  bf16x8 bq[4];
  #pragma unroll
  for (int cf = 0; cf < 4; ++cf) bq[cf] = *(const bf16x8*)(wtile + bBase[cf]);
  __syncthreads();

  #pragma unroll
  for (int kt = 0; kt < NKT; ++kt) {
    const int cur = kt & 1;
    bf16x8 bq2[4];
    float4 av2;
    if (kt + 1 < NKT) {                       // issue next B frags (L2-hot)
      const unsigned short* wtk = wtile + (kt + 1) * (BK * DIM);
      #pragma unroll
      for (int cf = 0; cf < 4; ++cf) bq2[cf] = *(const bf16x8*)(wtk + bBase[cf]);
    }
    if (kt + 2 < NKT)                         // issue x load 2 tiles ahead (HBM)
      av2 = *(const float4*)(aptr + (kt + 2) * BK);

    const unsigned short* asrc = &As[cur][0];
    #pragma unroll
    for (int rf = 0; rf < 4; ++rf) {
      bf16x8 af = *(const bf16x8*)&asrc[rf * 640 + a_off];
      #pragma unroll
      for (int cf = 0; cf < 4; ++cf)
        acc[rf][cf] = __builtin_amdgcn_mfma_f32_16x16x32_bf16(af, bq[cf], acc[rf][cf], 0, 0, 0);
    }

    if (kt + 1 < NKT) {                       // convert + write held x data
      ushort4 a4;
      a4.x = f2bf(av1.x); a4.y = f2bf(av1.y); a4.z = f2bf(av1.z); a4.w = f2bf(av1.w);
      *(ushort4*)&As[cur ^ 1][arow * 40 + kq * 4] = a4;
      #pragma unroll
      for (int cf = 0; cf < 4; ++cf) bq[cf] = bq2[cf];
    }
    if (kt + 2 < NKT) av1 = av2;
    __syncthreads();
  }

  // epilogue: bias add + scattered row store (16 consecutive cols per lane group)
  float bv[4];
  #pragma unroll
  for (int cf = 0; cf < 4; ++cf) bv[cf] = bias[b * DIM + w * 64 + cf * 16 + (l & 15)];
  const int rb = (l >> 4) * 4;
  #pragma unroll
  for (int rf = 0; rf < 4; ++rf) {
    #pragma unroll
    for (int j = 0; j < 4; ++j) {
      int r = rf * 16 + rb + j;
      if (r < vrows) {
        float* op = out + (size_t)rowIdx[r] * DIM + w * 64 + (l & 15);
        #pragma unroll
        for (int cf = 0; cf < 4; ++cf) op[cf * 16] = acc[rf][cf][j] + bv[cf];
      }
    }
  }
}

// ---------------- launcher ----------------
// ws layout: [0,32) counts | [64,96) cursors | [128,160) offsets |
//            [256, 256+4T) perm | [1MB, 1MB+4MB) Wt bf16
extern "C" void kernel_launch(void* const* d_in, const int* in_sizes, int n_in,
                              void* d_out, int out_size, void* d_ws, size_t ws_size,
                              hipStream_t stream) {
  const float* x    = (const float*)d_in[0];
  const int*   bidx = (const int*)d_in[1];
  const float* W    = (const float*)d_in[2];
  const float* bias = (const float*)d_in[3];
  float* out = (float*)d_out;

  char* ws = (char*)d_ws;
  int* counts  = (int*)(ws + 0);
  int* cursors = (int*)(ws + 64);
  int* offsets = (int*)(ws + 128);
  int* perm    = (int*)(ws + 256);
  unsigned short* Wt = (unsigned short*)(ws + (1u << 20));

  k_init<<<1, 64, 0, stream>>>(counts);
  k_bhist<<<T_TOK / 512, 512, 0, stream>>>(bidx, counts);
  k_off<<<1, 64, 0, stream>>>(counts, offsets, cursors);
  k_scatter<<<T_TOK / 512, 512, 0, stream>>>(bidx, cursors, perm);
  k_wtrans<<<512, 256, 0, stream>>>(W, Wt);
  k_gemm<<<NBR * MT, GT, 0, stream>>>(x, bias, Wt, counts, offsets, perm, out);
}

// Round 3
// 205.829 us; speedup vs baseline: 1.8686x; 1.0013x over previous
//
#include <hip/hip_runtime.h>
#include <hip/hip_bf16.h>
#include <stdint.h>

#define T_TOK 131072
#define DIM   512
#define NBR   8
#define BM    64
#define BK    32
#define NKT   (DIM / BK)   // 16
#define GT    512          // gemm threads (8 waves)
#define MT    288          // max row-tiles per branch

typedef __attribute__((ext_vector_type(8))) __bf16 bf16x8;
typedef __attribute__((ext_vector_type(4))) float  f32x4;
typedef unsigned short ushort_t;

__device__ __forceinline__ unsigned short f2bf(float f) {
  union { float f; unsigned int u; } v; v.f = f;
  unsigned int r = v.u + 0x7fffu + ((v.u >> 16) & 1u);
  return (unsigned short)(r >> 16);
}

// ---------------- prep kernels ----------------

__global__ void k_init(int* counts) {
  if (threadIdx.x < NBR) counts[threadIdx.x] = 0;
}

__global__ __launch_bounds__(512) void k_bhist(const int* __restrict__ bidx,
                                               int* __restrict__ counts) {
  __shared__ int h[NBR];
  if (threadIdx.x < NBR) h[threadIdx.x] = 0;
  __syncthreads();
  int t = blockIdx.x * 512 + threadIdx.x;
  atomicAdd(&h[bidx[t]], 1);
  __syncthreads();
  if (threadIdx.x < NBR) atomicAdd(&counts[threadIdx.x], h[threadIdx.x]);
}

__global__ void k_off(const int* __restrict__ counts, int* __restrict__ offsets,
                      int* __restrict__ cursors) {
  if (threadIdx.x == 0) {
    int s = 0;
    for (int n = 0; n < NBR; ++n) { offsets[n] = s; cursors[n] = s; s += counts[n]; }
  }
}

__global__ __launch_bounds__(512) void k_scatter(const int* __restrict__ bidx,
                                                 int* __restrict__ cursors,
                                                 int* __restrict__ perm) {
  __shared__ int h[NBR], base[NBR];
  if (threadIdx.x < NBR) h[threadIdx.x] = 0;
  __syncthreads();
  int t = blockIdx.x * 512 + threadIdx.x;
  int b = bidx[t];
  int rank = atomicAdd(&h[b], 1);
  __syncthreads();
  if (threadIdx.x < NBR)
    base[threadIdx.x] = atomicAdd(&cursors[threadIdx.x], h[threadIdx.x]);
  __syncthreads();
  perm[base[b] + rank] = t;
}

// W (N,D,D) fp32 row-major -> Wt bf16 tiled [b][kt][c][kk], kk = k % 32
__global__ __launch_bounds__(256) void k_wtrans(const float* __restrict__ W,
                                                ushort_t* __restrict__ Wt) {
  __shared__ float tile[BK][129];
  int blk = blockIdx.x;          // 8 * 16 * 4 = 512 blocks
  int b  = blk >> 6;
  int kt = (blk >> 2) & 15;
  int cb = blk & 3;
  int t = threadIdx.x;
  #pragma unroll
  for (int i = 0; i < 4; ++i) {
    int idx4 = i * 256 + t;
    int kr = idx4 >> 5;
    int c4 = idx4 & 31;
    const float* src = W + (((size_t)b * DIM + (size_t)(kt * BK + kr)) * DIM + cb * 128 + c4 * 4);
    float4 v = *(const float4*)src;
    tile[kr][c4 * 4 + 0] = v.x;
    tile[kr][c4 * 4 + 1] = v.y;
    tile[kr][c4 * 4 + 2] = v.z;
    tile[kr][c4 * 4 + 3] = v.w;
  }
  __syncthreads();
  int c  = t >> 1;
  int kh = t & 1;
  unsigned int p[8];
  #pragma unroll
  for (int i = 0; i < 8; ++i) {
    unsigned short lo = f2bf(tile[kh * 16 + i * 2 + 0][c]);
    unsigned short hi = f2bf(tile[kh * 16 + i * 2 + 1][c]);
    p[i] = (unsigned int)lo | ((unsigned int)hi << 16);
  }
  size_t obase = (((size_t)b * 16 + kt) * DIM + (size_t)(cb * 128 + c)) * BK + kh * 16;
  uint4 q0; q0.x = p[0]; q0.y = p[1]; q0.z = p[2]; q0.w = p[3];
  uint4 q1; q1.x = p[4]; q1.y = p[5]; q1.z = p[6]; q1.w = p[7];
  *(uint4*)&Wt[obase]     = q0;
  *(uint4*)&Wt[obase + 8] = q1;
}

// ---------------- grouped GEMM ----------------
// Block: 64 rows x 512 cols, 8 waves (wave 64x64), 16x16x32 MFMA.
// Phase 1: stage ALL of A (fp32 x -> bf16) into LDS, fragment-linear layout
//          (frag reads = base + lane*16B -> zero bank conflicts). ONE barrier.
// Phase 2: barrier-free k-loop; B frags straight from L2-resident Wt, depth-1.
// 2 blocks/CU (LDS 64.25KB, VGPR capped 128) so staging overlaps compute.
__global__ __launch_bounds__(GT, 4)
void k_gemm(const float* __restrict__ x, const float* __restrict__ bias,
            const ushort_t* __restrict__ Wt,
            const int* __restrict__ counts, const int* __restrict__ offsets,
            const int* __restrict__ perm, float* __restrict__ out) {
  // As[f][lane][8] : f = kt*4+rf, 16*4*64*8 ushorts = 64KB
  __shared__ __align__(16) ushort_t As[NKT * 4 * 64 * 8];
  __shared__ int rowIdx[BM];

  const int tid = threadIdx.x;
  const int l = tid & 63;
  const int w = tid >> 6;

  const int b  = blockIdx.x / MT;     // branch-major
  const int lt = blockIdx.x % MT;
  const int cnt = counts[b];
  const int row0 = lt * BM;
  if (row0 >= cnt) return;
  const int gstart = offsets[b];
  const int vrows = min(BM, cnt - row0);

  if (tid < BM) {
    int r = row0 + tid; if (r >= cnt) r = cnt - 1;
    rowIdx[tid] = perm[gstart + r];
  }
  __syncthreads();

  // ---- Phase 1: stage A ----
  // thread -> (row = tid>>3, kq = tid&7); element k-range per kt: kq*4..+4
  const int arow = tid >> 3;
  const int kq = tid & 7;
  const float* aptr = x + (size_t)rowIdx[arow] * DIM + kq * 4;
  // dest (ushorts) within a kt-slab: frag (arow>>4), lane-slot (kq>>1)*16+(arow&15), half (kq&1)
  const int wbase = (((arow >> 4) * 64) + (kq >> 1) * 16 + (arow & 15)) * 8 + (kq & 1) * 4;

  {
    float4 xa = *(const float4*)aptr;
    float4 xb = *(const float4*)(aptr + BK);
    #pragma unroll
    for (int i = 0; i < NKT; ++i) {
      float4 xn;
      if (i + 2 < NKT) xn = *(const float4*)(aptr + (i + 2) * BK);
      ushort4 a4;
      a4.x = f2bf(xa.x); a4.y = f2bf(xa.y); a4.z = f2bf(xa.z); a4.w = f2bf(xa.w);
      *(ushort4*)&As[i * 2048 + wbase] = a4;
      xa = xb; xb = xn;
    }
  }
  __syncthreads();

  // ---- Phase 2: barrier-free compute ----
  const ushort_t* wtile = Wt + (size_t)b * (NKT * BK * DIM);
  int bBase[4];
  #pragma unroll
  for (int cf = 0; cf < 4; ++cf)
    bBase[cf] = (w * 64 + cf * 16 + (l & 15)) * BK + (l >> 4) * 8;

  f32x4 acc[4][4];
  #pragma unroll
  for (int rf = 0; rf < 4; ++rf)
    #pragma unroll
    for (int cf = 0; cf < 4; ++cf) acc[rf][cf] = (f32x4){0.f, 0.f, 0.f, 0.f};

  bf16x8 bq[4];
  #pragma unroll
  for (int cf = 0; cf < 4; ++cf) bq[cf] = *(const bf16x8*)(wtile + bBase[cf]);

  #pragma unroll
  for (int kt = 0; kt < NKT; ++kt) {
    bf16x8 bqn[4];
    if (kt + 1 < NKT) {
      const ushort_t* wtk = wtile + (kt + 1) * (BK * DIM);
      #pragma unroll
      for (int cf = 0; cf < 4; ++cf) bqn[cf] = *(const bf16x8*)(wtk + bBase[cf]);
    }
    bf16x8 af[4];
    #pragma unroll
    for (int rf = 0; rf < 4; ++rf)
      af[rf] = *(const bf16x8*)&As[(kt * 4 + rf) * 512 + l * 8];
    #pragma unroll
    for (int cf = 0; cf < 4; ++cf)
      #pragma unroll
      for (int rf = 0; rf < 4; ++rf)
        acc[rf][cf] = __builtin_amdgcn_mfma_f32_16x16x32_bf16(af[rf], bq[cf], acc[rf][cf], 0, 0, 0);
    if (kt + 1 < NKT) {
      #pragma unroll
      for (int cf = 0; cf < 4; ++cf) bq[cf] = bqn[cf];
    }
  }

  // ---- epilogue ----
  float bv[4];
  #pragma unroll
  for (int cf = 0; cf < 4; ++cf) bv[cf] = bias[b * DIM + w * 64 + cf * 16 + (l & 15)];
  const int rb = (l >> 4) * 4;
  #pragma unroll
  for (int rf = 0; rf < 4; ++rf) {
    #pragma unroll
    for (int j = 0; j < 4; ++j) {
      int r = rf * 16 + rb + j;
      if (r < vrows) {
        float* op = out + (size_t)rowIdx[r] * DIM + w * 64 + (l & 15);
        #pragma unroll
        for (int cf = 0; cf < 4; ++cf) op[cf * 16] = acc[rf][cf][j] + bv[cf];
      }
    }
  }
}

// ---------------- launcher ----------------
// ws layout: [0,32) counts | [64,96) cursors | [128,160) offsets |
//            [256, 256+4T) perm | [1MB, 1MB+4MB) Wt bf16
extern "C" void kernel_launch(void* const* d_in, const int* in_sizes, int n_in,
                              void* d_out, int out_size, void* d_ws, size_t ws_size,
                              hipStream_t stream) {
  const float* x    = (const float*)d_in[0];
  const int*   bidx = (const int*)d_in[1];
  const float* W    = (const float*)d_in[2];
  const float* bias = (const float*)d_in[3];
  float* out = (float*)d_out;

  char* ws = (char*)d_ws;
  int* counts  = (int*)(ws + 0);
  int* cursors = (int*)(ws + 64);
  int* offsets = (int*)(ws + 128);
  int* perm    = (int*)(ws + 256);
  ushort_t* Wt = (ushort_t*)(ws + (1u << 20));

  k_init<<<1, 64, 0, stream>>>(counts);
  k_bhist<<<T_TOK / 512, 512, 0, stream>>>(bidx, counts);
  k_off<<<1, 64, 0, stream>>>(counts, offsets, cursors);
  k_scatter<<<T_TOK / 512, 512, 0, stream>>>(bidx, cursors, perm);
  k_wtrans<<<512, 256, 0, stream>>>(W, Wt);
  k_gemm<<<NBR * MT, GT, 0, stream>>>(x, bias, Wt, counts, offsets, perm, out);
}